// Round 6
// baseline (8318.995 us; speedup 1.0000x reference)
//
#include <hip/hip_runtime.h>
#include <hip/hip_bf16.h>

typedef __attribute__((ext_vector_type(8))) short bf16x8;
typedef __attribute__((ext_vector_type(4))) float f32x4;

constexpr int NB = 64, NS = 512, ND = 512, NH = 1024;
constexpr int KT  = ND + NH;       // 1536 unified K
constexpr int G4H = 4 * NH;        // 4096
constexpr int NWG = 256, NTHR = 512;
constexpr int NKQ = 12;            // k-steps per wave (384/32)
constexpr int PS  = 20;            // part[] row stride (floats)
constexpr int TRB = KT * 2;        // tile row stride bytes (3072)

__device__ inline unsigned short f2bf(float f) {
  union { float f; unsigned u; } v; v.f = f;
  unsigned r = v.u + 0x7FFFu + ((v.u >> 16) & 1u);  // RNE
  return (unsigned short)(r >> 16);
}
__device__ inline unsigned int pk2(float lo, float hi) {
  return (unsigned int)f2bf(lo) | ((unsigned int)f2bf(hi) << 16);
}
__device__ inline float sigmoidf_fast(float x) { return 1.0f / (1.0f + __expf(-x)); }
__device__ inline float tanhf_fast(float x) {
  float e = __expf(2.0f * x);
  return 1.0f - 2.0f / (e + 1.0f);
}
// XOR-swizzled byte offset within the unified A-tile (row stride 3072B, %128==0)
__device__ inline int sw(int row, int b) { return row * TRB + (b ^ ((row & 7) << 4)); }

__device__ inline uint4 cvt8(float4 a, float4 b) {
  uint4 r;
  r.x = pk2(a.x, a.y);
  r.y = pk2(a.z, a.w);
  r.z = pk2(b.x, b.y);
  r.w = pk2(b.z, b.w);
  return r;
}

// ---------------- prep: x -> bf16, zero flags ----------------
__global__ void prep_kernel(const float* __restrict__ x,
                            unsigned short* __restrict__ xbf,
                            unsigned int* __restrict__ flags) {
  const int idx = blockIdx.x * blockDim.x + threadIdx.x;
  const int nthr = gridDim.x * blockDim.x;
  for (int i = idx; i < NWG * 16; i += nthr) flags[i] = 0u;
  const float4* x4 = (const float4*)x;
  ushort4* xo = (ushort4*)xbf;
  const int n4 = NB * NS * ND / 4;
  for (int i = idx; i < n4; i += nthr) {
    float4 v = x4[i];
    ushort4 o;
    o.x = f2bf(v.x); o.y = f2bf(v.y); o.z = f2bf(v.z); o.w = f2bf(v.w);
    xo[i] = o;
  }
}

// ---------------- main persistent kernel ----------------
__global__ __launch_bounds__(NTHR)
void lstm_kernel(const float* __restrict__ Wih,
                 const float* __restrict__ Whh,
                 const float* __restrict__ bias,
                 const unsigned short* __restrict__ xbf,
                 unsigned int* __restrict__ flags,
                 float* __restrict__ out)
{
  const int tid  = threadIdx.x;
  const int wg   = blockIdx.x;
  const int wave = tid >> 6;
  const int lane = tid & 63;
  const int bb   = wg & 3;        // batch block (16 rows); also the barrier group
  const int hb   = wg >> 2;       // hidden block (16 cols)
  const int gp   = wave & 1;      // gate pair: 0 -> {i,f}, 1 -> {g,o}
  const int kq   = wave >> 1;     // K quarter: 384 of 1536

  __shared__ unsigned short tile[16 * KT];   // unified A-tile [16][1536] bf16, swizzled (48KB)
  __shared__ float part[16][16 * PS];        // partial gate tiles [wave*2+gg]
  __shared__ float c_state[256];

  if (tid < 256) c_state[tid] = 0.0f;

  // ---------- one-time weight B-frag gather ----------
  // B-frag: lane holds col = lane&15, k = kbase + (lane>>4)*8 + j
  const int kg0  = (lane >> 4) << 3;
  const int colb = (hb << 4) + (lane & 15);
  bf16x8 bfr[2][NKQ];
#pragma unroll
  for (int gg = 0; gg < 2; ++gg) {
    const int col = ((gp * 2 + gg) << 10) + colb;
    for (int s = 0; s < NKQ; ++s) {
      const int k0 = kq * 384 + s * 32 + kg0;
#pragma unroll
      for (int j = 0; j < 8; ++j) {
        const int k = k0 + j;
        const float w = (k < ND) ? Wih[(size_t)k * G4H + col]
                                 : Whh[(size_t)(k - ND) * G4H + col];
        bfr[gg][s][j] = (short)f2bf(w);
      }
    }
  }

  // ---------- prologue staging: x(0) into tile[:,0:512], zeros into tile[:,512:1536] ----
  {
    const int r  = tid >> 5;
    const int cx = (tid & 31) << 4;   // 16 x-cols per thread
    const unsigned short* src = xbf + (size_t)((bb << 4) + r) * (NS * ND) + cx;
    uint4 a = *(const uint4*)src;
    uint4 b = *(const uint4*)(src + 8);
    *(uint4*)((char*)tile + sw(r, cx * 2))      = a;
    *(uint4*)((char*)tile + sw(r, cx * 2 + 16)) = b;
    const int ch = (tid & 31) << 5;   // 32 h-cols per thread
#pragma unroll
    for (int u = 0; u < 4; ++u)
      *(uint4*)((char*)tile + sw(r, (ND + ch + u * 8) * 2)) = uint4{0, 0, 0, 0};
  }
  __syncthreads();

  const int arow_r = lane & 15;       // tile row for A-frags
  const int SX = (kq * 384 < ND) ? min(NKQ, (ND - kq * 384) / 32) : 0;  // pure-x k-steps
  float* ht_out = out + (size_t)NB * NS * NH;
  float* ct_out = ht_out + NB * NH;

  for (int t = 0; t < NS; ++t) {
    // ---- phase A: issue h(t-1) staging loads (L2-cached, write-once history in out) ----
    float4 v[8];
    const int sr = tid >> 5, sch = (tid & 31) << 5;
    if (t > 0) {
      const float4* hsrc = (const float4*)(out + (size_t)((bb << 4) + sr) * (NS * NH)
                                               + (size_t)(t - 1) * NH + sch);
#pragma unroll
      for (int u = 0; u < 8; ++u) v[u] = hsrc[u];
    }

    // ---- x-part MFMAs (hide h staging-load latency) ----
    f32x4 acc0 = {0.f, 0.f, 0.f, 0.f}, acc1 = {0.f, 0.f, 0.f, 0.f};
    for (int s = 0; s < SX; ++s) {
      const int k0 = kq * 384 + s * 32 + kg0;
      bf16x8 af = *(const bf16x8*)((const char*)tile + sw(arow_r, k0 * 2));
      acc0 = __builtin_amdgcn_mfma_f32_16x16x32_bf16(af, bfr[0][s], acc0, 0, 0, 0);
      acc1 = __builtin_amdgcn_mfma_f32_16x16x32_bf16(af, bfr[1][s], acc1, 0, 0, 0);
    }

    // ---- convert + ds_write h slice ----
    if (t > 0) {
#pragma unroll
      for (int u = 0; u < 4; ++u) {
        uint4 pk = cvt8(v[2 * u], v[2 * u + 1]);
        *(uint4*)((char*)tile + sw(sr, (ND + sch + u * 8) * 2)) = pk;
      }
    }
    __syncthreads();  // B: h region of tile ready

    // ---- h-part MFMAs ----
    for (int s = SX; s < NKQ; ++s) {
      const int k0 = kq * 384 + s * 32 + kg0;
      bf16x8 af = *(const bf16x8*)((const char*)tile + sw(arow_r, k0 * 2));
      acc0 = __builtin_amdgcn_mfma_f32_16x16x32_bf16(af, bfr[0][s], acc0, 0, 0, 0);
      acc1 = __builtin_amdgcn_mfma_f32_16x16x32_bf16(af, bfr[1][s], acc1, 0, 0, 0);
    }

    // C/D layout: col = lane&15, row = (lane>>4)*4 + reg
    {
      const int r0 = (lane >> 4) << 2;
      const int cc = lane & 15;
#pragma unroll
      for (int j = 0; j < 4; ++j) {
        part[wave * 2 + 0][(r0 + j) * PS + cc] = acc0[j];
        part[wave * 2 + 1][(r0 + j) * PS + cc] = acc1[j];
      }
    }
    __syncthreads();  // D

    // ---- epilogue: 256 threads, one (row,col) each ----
    if (tid < 256) {
      const int ec = tid & 15;
      const int er = tid >> 4;
      float pre[4];
#pragma unroll
      for (int go = 0; go < 4; ++go) {
        float s = bias[(go << 10) + (hb << 4) + ec];
#pragma unroll
        for (int q = 0; q < 4; ++q)
          s += part[(q * 2 + (go >> 1)) * 2 + (go & 1)][er * PS + ec];
        pre[go] = s;
      }
      const float it = sigmoidf_fast(pre[0]);
      const float ft = sigmoidf_fast(pre[1]);
      const float gt = tanhf_fast(pre[2]);
      const float ot = sigmoidf_fast(pre[3]);
      const float cn = ft * c_state[tid] + it * gt;
      c_state[tid] = cn;
      const float hn = ot * tanhf_fast(cn);
      const int row  = (bb << 4) + er;
      const int hcol = (hb << 4) + ec;
      // agent-scope packed fp32 pair store: h history + final output in one
      unsigned int my = __float_as_uint(hn);
      unsigned int pa = (unsigned int)__shfl_xor((int)my, 1, 64);
      if ((tid & 1) == 0) {
        unsigned long long pv = (unsigned long long)my | ((unsigned long long)pa << 32);
        __hip_atomic_store((unsigned long long*)(out + (size_t)row * (NS * NH)
                                                     + (size_t)t * NH + hcol),
                           pv, __ATOMIC_RELAXED, __HIP_MEMORY_SCOPE_AGENT);
      }
      if (t == NS - 1) {
        ht_out[row * NH + hcol] = hn;
        ct_out[row * NH + hcol] = cn;
      }
    }

    if (t < NS - 1) {
      // drain h stores (waves 0-3 hold them) before signaling
      if (wave < 4) asm volatile("s_waitcnt vmcnt(0)" ::: "memory");
      __syncthreads();  // F

      // phase G: flag + poll on wave 7; x(t+1) staging on waves 0-6
      if (tid == (7 << 6))
        __hip_atomic_store(flags + (size_t)wg * 16, (unsigned int)(t + 1),
                           __ATOMIC_RELAXED, __HIP_MEMORY_SCOPE_AGENT);
      if (wave == 7) {
        const unsigned int target = (unsigned int)(t + 1);
        const unsigned int* fp = flags + (size_t)((lane << 2) | bb) * 16;
        while (true) {
          unsigned int fv = __hip_atomic_load(fp, __ATOMIC_RELAXED, __HIP_MEMORY_SCOPE_AGENT);
          if (__all((int)(fv >= target))) break;
          __builtin_amdgcn_s_sleep(1);
        }
      } else {
        // 512 chunks of 16 x-cols over 448 threads
        for (int c = tid; c < 512; c += 448) {
          const int r  = c >> 5;
          const int cx = (c & 31) << 4;
          const unsigned short* src = xbf + (size_t)((bb << 4) + r) * (NS * ND)
                                          + (size_t)(t + 1) * ND + cx;
          uint4 a = *(const uint4*)src;
          uint4 b = *(const uint4*)(src + 8);
          *(uint4*)((char*)tile + sw(r, cx * 2))      = a;
          *(uint4*)((char*)tile + sw(r, cx * 2 + 16)) = b;
        }
      }
      __syncthreads();  // H: release into step t+1
    }
  }
}

extern "C" void kernel_launch(void* const* d_in, const int* in_sizes, int n_in,
                              void* d_out, int out_size, void* d_ws, size_t ws_size,
                              hipStream_t stream) {
  const float* x    = (const float*)d_in[0];
  const float* wih  = (const float*)d_in[1];
  const float* whh  = (const float*)d_in[2];
  const float* bias = (const float*)d_in[3];
  float* out = (float*)d_out;

  // ws layout: [flags 16KB][xbf NB*NS*ND bf16 = 32MB]
  unsigned int*   flags = (unsigned int*)d_ws;
  unsigned short* xbf   = (unsigned short*)((char*)d_ws + 16384);

  prep_kernel<<<1024, 256, 0, stream>>>(x, xbf, flags);

  void* args[] = { (void*)&wih, (void*)&whh, (void*)&bias,
                   (void*)&xbf, (void*)&flags, (void*)&out };
  hipLaunchCooperativeKernel((const void*)lstm_kernel, dim3(NWG), dim3(NTHR),
                             args, 0, stream);
}

// Round 7
// 1809.533 us; speedup vs baseline: 4.5973x; 4.5973x over previous
//
#include <hip/hip_runtime.h>
#include <hip/hip_bf16.h>

typedef __attribute__((ext_vector_type(8))) short bf16x8;
typedef __attribute__((ext_vector_type(4))) float f32x4;

constexpr int NB = 64, NS = 512, ND = 512, NH = 1024;
constexpr int G4H = 4096;
constexpr int NWG = 256, NTHR = 512;
constexpr int PS  = 20;            // part[] row stride (floats)
constexpr int TRB = 3072;          // tile row stride bytes (512*2 + 1024*2)

__device__ inline unsigned short f2bf(float f) {
  union { float f; unsigned u; } v; v.f = f;
  unsigned r = v.u + 0x7FFFu + ((v.u >> 16) & 1u);  // RNE
  return (unsigned short)(r >> 16);
}
__device__ inline float sigmoidf_fast(float x) { return 1.0f / (1.0f + __expf(-x)); }
__device__ inline float tanhf_fast(float x) {
  float e = __expf(2.0f * x);
  return 1.0f - 2.0f / (e + 1.0f);
}
// XOR-swizzle intra-row byte offset (involution, applied on write AND read)
__device__ inline int swz(int row, int off) { return row * TRB + (off ^ ((row & 7) << 4)); }

// ---------------- prep: x -> bf16, zero flags ----------------
__global__ void prep_kernel(const float* __restrict__ x,
                            unsigned short* __restrict__ xbf,
                            unsigned int* __restrict__ flags) {
  const int idx = blockIdx.x * blockDim.x + threadIdx.x;
  const int nthr = gridDim.x * blockDim.x;
  for (int i = idx; i < NWG * 16; i += nthr) flags[i] = 0u;
  const float4* x4 = (const float4*)x;
  ushort4* xo = (ushort4*)xbf;
  const int n4 = NB * NS * ND / 4;
  for (int i = idx; i < n4; i += nthr) {
    float4 v = x4[i];
    ushort4 o;
    o.x = f2bf(v.x); o.y = f2bf(v.y); o.z = f2bf(v.z); o.w = f2bf(v.w);
    xo[i] = o;
  }
}

// ---------------- main persistent kernel ----------------
__global__ __launch_bounds__(NTHR)
void lstm_kernel(const float* __restrict__ Wih,
                 const float* __restrict__ Whh,
                 const float* __restrict__ bias,
                 const unsigned short* __restrict__ xbf,
                 unsigned short* __restrict__ hbuf,   // 2 ping-pong NB*NH bf16 (LLC)
                 unsigned int* __restrict__ flags,
                 float* __restrict__ out)
{
  const int tid  = threadIdx.x;
  const int wg   = blockIdx.x;
  const int wave = tid >> 6;
  const int lane = tid & 63;
  const int bb   = wg >> 6;       // batch block (hb-major: XCD-chunk locality)
  const int hb   = wg & 63;       // hidden block (16 cols)
  const int gp   = wave & 1;      // gate pair: 0 -> {i,f}, 1 -> {g,o}
  const int q    = wave >> 1;     // K quarter (owns x-ksteps 4q..4q+3, h-ksteps 8q..8q+7)

  __shared__ unsigned short tile[16 * 1536];  // [16][512 x | 1024 h] bf16, swizzled (48KB)
  __shared__ float part[16][16 * PS];
  __shared__ float c_state[256];

  if (tid < 256) c_state[tid] = 0.0f;

  // ---------- one-time weight B-frag gather (col = lane&15, k = kbase+(lane>>4)*8+j) ----
  const int kg0  = (lane >> 4) << 3;
  const int colb = (hb << 4) + (lane & 15);
  bf16x8 wx[2][4], wh[2][8];
#pragma unroll
  for (int gg = 0; gg < 2; ++gg) {
    const int col = ((gp * 2 + gg) << 10) + colb;
#pragma unroll
    for (int s = 0; s < 4; ++s) {
      const int k0 = (q * 4 + s) * 32 + kg0;
#pragma unroll
      for (int j = 0; j < 8; ++j)
        wx[gg][s][j] = (short)f2bf(Wih[(size_t)(k0 + j) * G4H + col]);
    }
#pragma unroll
    for (int u = 0; u < 8; ++u) {
      const int k0 = (q * 8 + u) * 32 + kg0;
#pragma unroll
      for (int j = 0; j < 8; ++j)
        wh[gg][u][j] = (short)f2bf(Whh[(size_t)(k0 + j) * G4H + col]);
    }
  }

  // ---------- prologue: stage x(0); zero h region ----------
  for (int c = tid; c < 1024; c += NTHR) {       // 16 rows x 64 slots(16B) of x
    const int row = c >> 6, sl = c & 63;
    const unsigned short* src = xbf + (size_t)(bb * 16 + row) * (NS * ND) + sl * 8;
    *(uint4*)((char*)tile + swz(row, sl * 16)) = *(const uint4*)src;
  }
  for (int c = tid; c < 2048; c += NTHR) {       // 16 rows x 128 slots of h
    const int row = c >> 7, sl = c & 127;
    *(uint4*)((char*)tile + swz(row, 1024 + sl * 16)) = uint4{0, 0, 0, 0};
  }
  __syncthreads();

  const int arow = lane & 15;
  float* ht_out = out + (size_t)NB * NS * NH;
  float* ct_out = ht_out + NB * NH;

  for (int t = 0; t < NS; ++t) {
    // ---- P1: issue sc1 h(t-1) loads (4 slots of 16B per thread, all in flight) ----
    unsigned long long hq0[4], hq1[4];
    if (t > 0) {
#pragma unroll
      for (int u = 0; u < 4; ++u) {
        const int row = 2 * wave + (u >> 1);
        const int sl  = (u & 1) * 64 + lane;
        const unsigned long long* p = (const unsigned long long*)
            (hbuf + (size_t)(t & 1) * (NB * NH) + (size_t)(bb * 16 + row) * NH + sl * 8);
        hq0[u] = __hip_atomic_load(p,     __ATOMIC_RELAXED, __HIP_MEMORY_SCOPE_AGENT);
        hq1[u] = __hip_atomic_load(p + 1, __ATOMIC_RELAXED, __HIP_MEMORY_SCOPE_AGENT);
      }
    }

    // ---- P2: x-part MFMAs (every wave has 8 — hides h-load latency) ----
    f32x4 a0 = {0.f, 0.f, 0.f, 0.f}, a1 = {0.f, 0.f, 0.f, 0.f};
#pragma unroll
    for (int s = 0; s < 4; ++s) {
      const int off = ((q * 4 + s) * 32 + kg0) * 2;
      bf16x8 af = *(const bf16x8*)((const char*)tile + swz(arow, off));
      a0 = __builtin_amdgcn_mfma_f32_16x16x32_bf16(af, wx[0][s], a0, 0, 0, 0);
      a1 = __builtin_amdgcn_mfma_f32_16x16x32_bf16(af, wx[1][s], a1, 0, 0, 0);
    }

    // ---- P3: ds_write h slice (lane-contiguous 16B per quarter-wave: 2-way max) ----
    if (t > 0) {
#pragma unroll
      for (int u = 0; u < 4; ++u) {
        const int row = 2 * wave + (u >> 1);
        const int sl  = (u & 1) * 64 + lane;
        uint4 v;
        v.x = (unsigned int)hq0[u];
        v.y = (unsigned int)(hq0[u] >> 32);
        v.z = (unsigned int)hq1[u];
        v.w = (unsigned int)(hq1[u] >> 32);
        *(uint4*)((char*)tile + swz(row, 1024 + sl * 16)) = v;
      }
    }
    __syncthreads();  // P4: h region ready

    // ---- P5: h-part MFMAs ----
#pragma unroll
    for (int u = 0; u < 8; ++u) {
      const int off = 1024 + ((q * 8 + u) * 32 + kg0) * 2;
      bf16x8 af = *(const bf16x8*)((const char*)tile + swz(arow, off));
      a0 = __builtin_amdgcn_mfma_f32_16x16x32_bf16(af, wh[0][u], a0, 0, 0, 0);
      a1 = __builtin_amdgcn_mfma_f32_16x16x32_bf16(af, wh[1][u], a1, 0, 0, 0);
    }

    // ---- P6: partial tiles (C/D: col = lane&15, row = (lane>>4)*4 + reg) ----
    {
      const int r0 = (lane >> 4) << 2;
      const int cc = lane & 15;
#pragma unroll
      for (int j = 0; j < 4; ++j) {
        part[wave * 2 + 0][(r0 + j) * PS + cc] = a0[j];
        part[wave * 2 + 1][(r0 + j) * PS + cc] = a1[j];
      }
    }
    __syncthreads();  // P6b

    // ---- P7: epilogue (256 threads) ----
    if (tid < 256) {
      const int ec = tid & 15;
      const int er = tid >> 4;
      float pre[4];
#pragma unroll
      for (int go = 0; go < 4; ++go) {
        float s = bias[(go << 10) + (hb << 4) + ec];
#pragma unroll
        for (int qq = 0; qq < 4; ++qq)
          s += part[(qq * 2 + (go >> 1)) * 2 + (go & 1)][er * PS + ec];
        pre[go] = s;
      }
      const float it = sigmoidf_fast(pre[0]);
      const float ft = sigmoidf_fast(pre[1]);
      const float gt = tanhf_fast(pre[2]);
      const float ot = sigmoidf_fast(pre[3]);
      const float cn = ft * c_state[tid] + it * gt;
      c_state[tid] = cn;
      const float hn = ot * tanhf_fast(cn);
      const int row  = (bb << 4) + er;
      const int hcol = (hb << 4) + ec;
      // bf16 pair -> one sc1 u32 store into LLC h-exchange buffer
      unsigned int my = (unsigned int)f2bf(hn);
      unsigned int pa = (unsigned int)__shfl_xor((int)my, 1, 64);
      if ((tid & 1) == 0) {
        unsigned int* p = (unsigned int*)(hbuf + (size_t)((t + 1) & 1) * (NB * NH)
                                               + (size_t)row * NH + hcol);
        __hip_atomic_store(p, my | (pa << 16), __ATOMIC_RELAXED, __HIP_MEMORY_SCOPE_AGENT);
      }
      // streaming fp32 output store (never re-read by the kernel)
      __builtin_nontemporal_store(hn, &out[(size_t)row * (NS * NH) + (size_t)t * NH + hcol]);
      if (t == NS - 1) {
        ht_out[row * NH + hcol] = hn;
        ct_out[row * NH + hcol] = cn;
      }
    }

    if (t < NS - 1) {
      // P8: drain waves 0-3's h stores, then make them WG-visible
      if (wave < 4) asm volatile("s_waitcnt vmcnt(0)" ::: "memory");
      __syncthreads();

      // P9: flag + poll on wave 7; x(t+1) staging on waves 0-6
      if (tid == (7 << 6))
        __hip_atomic_store(flags + (size_t)wg * 16, (unsigned int)(t + 1),
                           __ATOMIC_RELAXED, __HIP_MEMORY_SCOPE_AGENT);
      if (wave == 7) {
        const unsigned int target = (unsigned int)(t + 1);
        const unsigned int* fp = flags + (size_t)((bb << 6) | lane) * 16;
        while (true) {
          unsigned int fv = __hip_atomic_load(fp, __ATOMIC_RELAXED, __HIP_MEMORY_SCOPE_AGENT);
          if (__all((int)(fv >= target))) break;
          __builtin_amdgcn_s_sleep(1);
        }
      } else {
        for (int c = tid; c < 1024; c += 448) {
          const int row = c >> 6, sl = c & 63;
          const unsigned short* src = xbf + (size_t)(bb * 16 + row) * (NS * ND)
                                          + (size_t)(t + 1) * ND + sl * 8;
          *(uint4*)((char*)tile + swz(row, sl * 16)) = *(const uint4*)src;
        }
      }
      __syncthreads();  // P10: release into step t+1
    }
  }
}

extern "C" void kernel_launch(void* const* d_in, const int* in_sizes, int n_in,
                              void* d_out, int out_size, void* d_ws, size_t ws_size,
                              hipStream_t stream) {
  const float* x    = (const float*)d_in[0];
  const float* wih  = (const float*)d_in[1];
  const float* whh  = (const float*)d_in[2];
  const float* bias = (const float*)d_in[3];
  float* out = (float*)d_out;

  // ws layout: [flags 16KB][hbuf 2*NB*NH bf16 = 256KB][xbf NB*NS*ND bf16 = 32MB]
  unsigned int*   flags = (unsigned int*)d_ws;
  unsigned short* hbuf  = (unsigned short*)((char*)d_ws + 16384);
  unsigned short* xbf   = (unsigned short*)((char*)d_ws + 16384 + (size_t)2 * NB * NH * 2);

  prep_kernel<<<1024, 256, 0, stream>>>(x, xbf, flags);

  void* args[] = { (void*)&wih, (void*)&whh, (void*)&bias,
                   (void*)&xbf, (void*)&hbuf, (void*)&flags, (void*)&out };
  hipLaunchCooperativeKernel((const void*)lstm_kernel, dim3(NWG), dim3(NTHR),
                             args, 0, stream);
}